// Round 5
// baseline (294.828 us; speedup 1.0000x reference)
//
#include <hip/hip_runtime.h>
#include <hip/hip_bf16.h>
#include <hip/hip_fp16.h>

// Problem constants
#define BQ    256
#define NKEY  100000
#define DD    512
#define AD    256
#define CD    100
#define KSEL  32
#define KB    64            // keys per K1 block
#define NB    1563          // ceil(NKEY/KB)
#define CPQ   (NB*12)       // cand entries per query = 18756

// k2a/k2b selection params
#define NPART 8             // k2a blocks per query
#define WTOP  12            // per-wave top list emitted by k2a
#define NC2   (NPART*4*WTOP)  // 384 rescore candidates per query
#define TLA   6             // per-lane list depth in k2a

typedef __attribute__((ext_vector_type(8))) short  short8_t;
typedef __attribute__((ext_vector_type(8))) __bf16 bf16x8;
typedef __attribute__((ext_vector_type(4))) float  f32x4;

__device__ __forceinline__ unsigned short f2bf(float x) {
  unsigned int u = __float_as_uint(x);
  return (unsigned short)((u + 0x7FFFu + ((u >> 16) & 1u)) >> 16);  // RTNE
}
__device__ __forceinline__ unsigned short f2bf_n(float x) {
  __bf16 h = (__bf16)x;                 // native cvt, pairs into v_cvt_pk_bf16_f32
  return __builtin_bit_cast(unsigned short, h);
}
__device__ __forceinline__ float bf2f(unsigned short h) {
  return __uint_as_float(((unsigned int)h) << 16);
}
__device__ __forceinline__ f32x4 mfma_bf16(short8_t a, short8_t b, f32x4 c) {
  return __builtin_amdgcn_mfma_f32_16x16x32_bf16(
      __builtin_bit_cast(bf16x8, a), __builtin_bit_cast(bf16x8, b), c, 0, 0, 0);
}
__device__ __forceinline__ float fast_tanh(float x) {
  x = fminf(fmaxf(x, -15.f), 15.f);
  float e = __expf(2.f * x);
  return (e - 1.f) * __builtin_amdgcn_rcpf(e + 1.f);
}

template<int T>
__device__ __forceinline__ void topk_insert(float (&v)[T], int (&ix)[T], float val, int idx) {
  if (val <= v[T-1]) return;
  v[T-1] = val; ix[T-1] = idx;
  #pragma unroll
  for (int j = T-1; j > 0; --j) {
    bool sw = v[j] > v[j-1];
    float tv = sw ? v[j] : v[j-1];  float uv = sw ? v[j-1] : v[j];
    int   ti = sw ? ix[j] : ix[j-1]; int  ui = sw ? ix[j-1] : ix[j];
    v[j-1] = tv; v[j] = uv; ix[j-1] = ti; ix[j] = ui;
  }
}

// ---------------- K0: q = relu(query_feat); qn; q -> bf16 fragment layout ----------------
__global__ __launch_bounds__(256) void k0_prep(const float* __restrict__ qfeat,
                                               float* __restrict__ qr,
                                               unsigned short* __restrict__ qf,
                                               float* __restrict__ qn) {
  int b = blockIdx.x, t = threadIdx.x;
  float s = 0.f;
  #pragma unroll
  for (int p = 0; p < 2; ++p) {
    int k = t + p*256;
    float v = qfeat[b*DD + k];
    v = v > 0.f ? v : 0.f;
    qr[b*DD + k] = v;
    qf[(((b>>4)*64 + (k>>3))*16 + (b&15))*8 + (k&7)] = f2bf(v);
    s += v*v;
  }
  __shared__ float red[4];
  #pragma unroll
  for (int st = 1; st < 64; st <<= 1) s += __shfl_xor(s, st, 64);
  if ((t & 63) == 0) red[t>>6] = s;
  __syncthreads();
  if (t == 0) qn[b] = sqrtf(red[0]+red[1]+red[2]+red[3]);
}

// ---------------- K0b: [512,256] fp32 matrix -> bf16 B-fragment layout ----------------
__global__ __launch_bounds__(256) void k0b_frag(const float* __restrict__ W,
                                                unsigned short* __restrict__ wf) {
  int i = blockIdx.x*256 + threadIdx.x;   // i = d*256 + a, 131072 total
  int d = i >> 8, a = i & 255;
  wf[(((a>>4)*64 + (d>>3))*16 + (a&15))*8 + (d&7)] = f2bf(W[i]);
}

// ---------------- K_qq: qq = relu(q) @ Wq + bq + bm  (256x256, K=512 MFMA) ----------------
__global__ __launch_bounds__(256) void k_qq(const float* __restrict__ Wq,
                                            const unsigned short* __restrict__ qf,
                                            const float* __restrict__ bq,
                                            const float* __restrict__ bm,
                                            float* __restrict__ qq) {
  __shared__ unsigned short wb[64*16*8];   // 16 KB
  int bn = blockIdx.x, t = threadIdx.x;
  int w = t >> 6, l = t & 63, g = l >> 4, c = l & 15;
  #pragma unroll
  for (int i = 0; i < 32; ++i) {
    int d = i*16 + (t>>4); int a = t & 15;
    wb[((d>>3)*16 + a)*8 + (d&7)] = f2bf(Wq[d*AD + bn*16 + a]);
  }
  __syncthreads();
  const short8_t* qf8 = (const short8_t*)qf;
  const short8_t* wb8 = (const short8_t*)wb;
  f32x4 acc[4];
  #pragma unroll
  for (int m = 0; m < 4; ++m) acc[m] = (f32x4){0.f,0.f,0.f,0.f};
  for (int kt = 0; kt < 16; ++kt) {
    short8_t bfr = wb8[(kt*4 + g)*16 + c];
    #pragma unroll
    for (int m = 0; m < 4; ++m) {
      short8_t afr = qf8[((w*4 + m)*64 + kt*4 + g)*16 + c];
      acc[m] = mfma_bf16(afr, bfr, acc[m]);
    }
  }
  int col = bn*16 + c;
  float bias = bq[col] + bm[col];
  #pragma unroll
  for (int m = 0; m < 4; ++m)
    #pragma unroll
    for (int r = 0; r < 4; ++r)
      qq[(w*64 + m*16 + g*4 + r)*AD + col] = acc[m][r] + bias;
}

// ---------------- K1: zero-LDS coarse bf16 GEMM (keys=A from global, queries=B) ----------------
__global__ __launch_bounds__(256) void k1_sim(const float* __restrict__ keys,
                                              const unsigned short* __restrict__ qf,
                                              unsigned int* __restrict__ cand) {
  __shared__ float invkn[64];

  int b = blockIdx.x, t = threadIdx.x;
  int kb0 = b*KB;
  int w = t >> 6, l = t & 63, g = l >> 4, c = l & 15;

  f32x4 acc[4][4];   // [key-tile m][query-tile n]
  #pragma unroll
  for (int m = 0; m < 4; ++m)
    #pragma unroll
    for (int n = 0; n < 4; ++n) acc[m][n] = (f32x4){0.f,0.f,0.f,0.f};
  float ksqm[4] = {0.f,0.f,0.f,0.f};

  // per-m clamped row base (lane reads 8 consecutive fp32 of its A-frag row)
  const float* abase[4];
  #pragma unroll
  for (int m = 0; m < 4; ++m) {
    int row = kb0 + m*16 + c;
    row = row < NKEY ? row : NKEY-1;
    abase[m] = keys + (size_t)row*DD + g*8;
  }
  const short8_t* qf8 = (const short8_t*)qf;
  bool w0 = (w == 0);

  #pragma unroll 2
  for (int st8 = 0; st8 < 8; ++st8) {
    #pragma unroll
    for (int ks = 0; ks < 2; ++ks) {
      // B fragments (queries, L2-resident)
      short8_t bfr[4];
      int kt = st8*8 + ks*4 + g;
      #pragma unroll
      for (int n = 0; n < 4; ++n) bfr[n] = qf8[((w*4 + n)*64 + kt)*16 + c];
      // A fragments direct from global, convert in-register
      #pragma unroll
      for (int m = 0; m < 4; ++m) {
        const float4* ap = (const float4*)(abase[m] + st8*64 + ks*32);
        float4 a0 = ap[0], a1 = ap[1];
        if (w0) {
          ksqm[m] += a0.x*a0.x + a0.y*a0.y + a0.z*a0.z + a0.w*a0.w
                   + a1.x*a1.x + a1.y*a1.y + a1.z*a1.z + a1.w*a1.w;
        }
        short8_t af;
        af[0] = (short)f2bf_n(a0.x); af[1] = (short)f2bf_n(a0.y);
        af[2] = (short)f2bf_n(a0.z); af[3] = (short)f2bf_n(a0.w);
        af[4] = (short)f2bf_n(a1.x); af[5] = (short)f2bf_n(a1.y);
        af[6] = (short)f2bf_n(a1.z); af[7] = (short)f2bf_n(a1.w);
        #pragma unroll
        for (int n = 0; n < 4; ++n) acc[m][n] = mfma_bf16(af, bfr[n], acc[m][n]);
      }
    }
  }

  // key inverse norms: wave 0 reduces over g-lanes (l^16, l^32 share the same row c)
  if (w0) {
    #pragma unroll
    for (int m = 0; m < 4; ++m) {
      float s = ksqm[m];
      s += __shfl_xor(s, 16, 64);
      s += __shfl_xor(s, 32, 64);
      if (l < 16) invkn[m*16 + l] = s > 0.f ? rsqrtf(s) : 0.f;
    }
  }
  __syncthreads();

  float ikv[16];
  #pragma unroll
  for (int m = 0; m < 4; ++m)
    #pragma unroll
    for (int r = 0; r < 4; ++r) ikv[m*4 + r] = invkn[m*16 + g*4 + r];

  // per-lane branchless top-3 of the lane's 16 keys, per query column
  #pragma unroll
  for (int n = 0; n < 4; ++n) {
    float v1 = -3.0e38f, v2 = -3.0e38f, v3 = -3.0e38f;
    int   i1 = 0, i2 = 0, i3 = 0;
    #pragma unroll
    for (int m = 0; m < 4; ++m)
      #pragma unroll
      for (int r = 0; r < 4; ++r) {
        int lid = m*16 + g*4 + r;
        bool valid = (kb0 + lid) < NKEY;
        float v = valid ? acc[m][n][r] * ikv[m*4 + r] : -3.0e38f;
        bool gt1 = v > v1, gt2 = v > v2, gt3 = v > v3;
        v3 = gt2 ? v2 : (gt3 ? v : v3);  i3 = gt2 ? i2 : (gt3 ? lid : i3);
        v2 = gt1 ? v1 : (gt2 ? v : v2);  i2 = gt1 ? i1 : (gt2 ? lid : i2);
        v1 = gt1 ? v  : v1;              i1 = gt1 ? lid : i1;
      }
    int q = w*64 + n*16 + c;
    unsigned int base = ((unsigned int)q*NB + (unsigned int)b)*12u + (unsigned int)g*3u;
    cand[base + 0] = ((unsigned int)__half_as_ushort(__float2half(v1)) << 16) | (unsigned int)i1;
    cand[base + 1] = ((unsigned int)__half_as_ushort(__float2half(v2)) << 16) | (unsigned int)i2;
    cand[base + 2] = ((unsigned int)__half_as_ushort(__float2half(v3)) << 16) | (unsigned int)i3;
  }
}

// ---------------- K2a: high-occupancy candidate reduce (8 blocks/query, per-wave top-12) ----------------
__global__ __launch_bounds__(256) void k2a_reduce(const unsigned int* __restrict__ cand,
                                                  int* __restrict__ wtop) {
  int bid = blockIdx.x;
  int q = bid >> 3, p = bid & 7;
  int t = threadIdx.x, w = t >> 6, l = t & 63;
  const unsigned int* cq = cand + (size_t)q * CPQ;

  const int PER_PART = (CPQ + NPART - 1) / NPART;   // 2345
  const int PER_WAVE = (PER_PART + 3) / 4;          // 587
  int pbase = p * PER_PART;
  int start = pbase + w * PER_WAVE;
  int end   = pbase + PER_PART;
  if (start + PER_WAVE < end) end = start + PER_WAVE;
  if (end > CPQ) end = CPQ;

  float v[TLA]; int ix[TLA];
  #pragma unroll
  for (int j = 0; j < TLA; ++j) { v[j] = -INFINITY; ix[j] = -1; }
  for (int i = start + l; i < end; i += 64) {
    unsigned int pk = cq[i];
    float val = __half2float(__ushort_as_half((unsigned short)(pk >> 16)));
    int bb = i / 12;                       // compiler magic-mul
    int idx = (bb << 6) | (int)(pk & 63u);
    topk_insert<TLA>(v, ix, val, idx);
  }

  // wave merge: exact wave top-WTOP (heads of sorted per-lane lists)
  int obase = (q * NPART + p) * 4 * WTOP + w * WTOP;
  for (int it = 0; it < WTOP; ++it) {
    float bv = v[0]; int bx = ix[0]; int bl = l;
    #pragma unroll
    for (int sft = 1; sft < 64; sft <<= 1) {
      float ov = __shfl_xor(bv, sft, 64);
      int  oxx = __shfl_xor(bx, sft, 64);
      int  ol  = __shfl_xor(bl, sft, 64);
      bool take = (ov > bv) || (ov == bv && ol < bl);
      if (take) { bv = ov; bx = oxx; bl = ol; }
    }
    if (l == 0) wtop[obase + it] = bx;
    if (l == bl) {
      #pragma unroll
      for (int j = 0; j < TLA-1; ++j) { v[j] = v[j+1]; ix[j] = ix[j+1]; }
      v[TLA-1] = -INFINITY; ix[TLA-1] = -1;
    }
  }
}

// ---------------- K2b: exact fp32 rescore of 384 (pipelined) + final top-32 ----------------
__global__ __launch_bounds__(256) void k2b_rescore(const int* __restrict__ wtop,
                                                   const float* __restrict__ qr,
                                                   const float* __restrict__ qn,
                                                   const float* __restrict__ keys,
                                                   int* __restrict__ fidx) {
  int q = blockIdx.x, t = threadIdx.x, w = t >> 6, l = t & 63;
  __shared__ int   cidL[NC2];
  __shared__ float simx[NC2];
  __shared__ int   sidx[NC2];

  // FIX: NC2=384 > blockDim=256 — stage with a stride loop (was `if (t < NC2)`,
  // leaving entries 256..383 as uninitialized LDS -> wild OOB key reads -> abort)
  for (int i = t; i < NC2; i += 256) {
    int idx = wtop[q*NC2 + i];
    cidL[i] = (idx < 0 || idx >= NKEY) ? -1 : idx;
  }
  __syncthreads();

  // each lane holds its 8-float slice of the query row
  const float4* q4 = (const float4*)(qr + (size_t)q*DD + l*8);
  float4 qa0 = q4[0], qa1 = q4[1];
  float qnv = qn[q];

  // two-deep pipeline: row loads for candidate i+1 overlap reduce of i
  int idx = cidL[w];
  const float4* kr = (const float4*)(keys + (size_t)(idx < 0 ? 0 : idx)*DD + l*8);
  float4 k0 = kr[0], k1 = kr[1];
  for (int i = 0; i < NC2/4; ++i) {
    int ci = i*4 + w;
    int curidx = idx;
    float4 c0 = k0, c1 = k1;
    if (i + 1 < NC2/4) {
      idx = cidL[(i+1)*4 + w];
      kr = (const float4*)(keys + (size_t)(idx < 0 ? 0 : idx)*DD + l*8);
      k0 = kr[0]; k1 = kr[1];
    }
    float dot = qa0.x*c0.x + qa0.y*c0.y + qa0.z*c0.z + qa0.w*c0.w
              + qa1.x*c1.x + qa1.y*c1.y + qa1.z*c1.z + qa1.w*c1.w;
    float ks  = c0.x*c0.x + c0.y*c0.y + c0.z*c0.z + c0.w*c0.w
              + c1.x*c1.x + c1.y*c1.y + c1.z*c1.z + c1.w*c1.w;
    #pragma unroll
    for (int sft = 1; sft < 64; sft <<= 1) {
      dot += __shfl_xor(dot, sft, 64);
      ks  += __shfl_xor(ks,  sft, 64);
    }
    if (l == 0) {
      float den = fmaxf(qnv * sqrtf(ks), 1e-8f);
      simx[ci] = (curidx < 0) ? -1e30f : dot/den;
      sidx[ci] = (curidx < 0) ? 0 : curidx;
    }
  }
  __syncthreads();

  // wave 0: exact top-32 of 384, tie-break value desc then index asc (lax.top_k)
  if (w == 0) {
    float a[6]; int id[6];
    #pragma unroll
    for (int j = 0; j < 6; ++j) { a[j] = simx[j*64 + l]; id[j] = sidx[j*64 + l]; }
    for (int it = 0; it < KSEL; ++it) {
      float bv = a[0]; int bx = id[0]; int bslot = 0;
      #pragma unroll
      for (int j = 1; j < 6; ++j) {
        bool take = (a[j] > bv) || (a[j] == bv && id[j] < bx);
        bv = take ? a[j] : bv; bx = take ? id[j] : bx; bslot = take ? j : bslot;
      }
      int bl = l;
      #pragma unroll
      for (int sft = 1; sft < 64; sft <<= 1) {
        float ov = __shfl_xor(bv, sft, 64);
        int  oxx = __shfl_xor(bx, sft, 64);
        int  ol  = __shfl_xor(bl, sft, 64);
        bool take = (ov > bv) || (ov == bv && oxx < bx);
        if (take) { bv = ov; bx = oxx; bl = ol; }
      }
      if (l == 0) fidx[q*KSEL + it] = bx;
      if (l == bl) {
        #pragma unroll
        for (int j = 0; j < 6; ++j) if (j == bslot) a[j] = -INFINITY;
      }
    }
  }
}

// ---------------- K3a: gather knn, MFMA knn@Wm, tanh/score/softmax, attended -> attf ----------------
__global__ __launch_bounds__(256) void k3_attn(const float* __restrict__ keys,
                                               const float* __restrict__ qq,
                                               const unsigned short* __restrict__ wmf,
                                               const int* __restrict__ fidx,
                                               const float* __restrict__ Ws,
                                               const float* __restrict__ bsc,
                                               unsigned short* __restrict__ attf) {
  int q = blockIdx.x, t = threadIdx.x, w = t >> 6, l = t & 63, g = l >> 4, c = l & 15;
  __shared__ float qqb[256];
  __shared__ float wsl[256];
  __shared__ unsigned short knnb[32*520];
  __shared__ float spart[4][32];
  __shared__ float wexp[32];
  __shared__ int fl[32];

  if (t < 32) fl[t] = fidx[q*KSEL + t];
  qqb[t] = qq[q*AD + t];
  wsl[t] = Ws[t];
  __syncthreads();

  for (int r = 0; r < 32; ++r) {
    int row = fl[r];
    #pragma unroll
    for (int p = 0; p < 2; ++p) {
      int d = t + p*256;
      knnb[r*520 + d] = f2bf(keys[(size_t)row*DD + d]);
    }
  }
  __syncthreads();

  f32x4 acc[2][4];
  #pragma unroll
  for (int m = 0; m < 2; ++m)
    #pragma unroll
    for (int n = 0; n < 4; ++n) acc[m][n] = (f32x4){0.f,0.f,0.f,0.f};
  const short8_t* wmf8 = (const short8_t*)wmf;
  for (int ks = 0; ks < 16; ++ks) {
    short8_t af[2], bf[4];
    #pragma unroll
    for (int m = 0; m < 2; ++m) af[m] = *(const short8_t*)&knnb[(m*16 + c)*520 + ks*32 + g*8];
    #pragma unroll
    for (int n = 0; n < 4; ++n) bf[n] = wmf8[((w*4 + n)*64 + ks*4 + g)*16 + c];
    #pragma unroll
    for (int m = 0; m < 2; ++m)
      #pragma unroll
      for (int n = 0; n < 4; ++n) acc[m][n] = mfma_bf16(af[m], bf[n], acc[m][n]);
  }

  float p[8] = {0.f,0.f,0.f,0.f,0.f,0.f,0.f,0.f};
  #pragma unroll
  for (int n = 0; n < 4; ++n) {
    int a = w*64 + n*16 + c;
    float qv = qqb[a], wv = wsl[a];
    #pragma unroll
    for (int m = 0; m < 2; ++m)
      #pragma unroll
      for (int r = 0; r < 4; ++r)
        p[m*4 + r] += fast_tanh(acc[m][n][r] + qv) * wv;
  }
  #pragma unroll
  for (int sft = 1; sft < 16; sft <<= 1)
    #pragma unroll
    for (int i = 0; i < 8; ++i) p[i] += __shfl_xor(p[i], sft, 64);
  if (c == 0) {
    #pragma unroll
    for (int m = 0; m < 2; ++m)
      #pragma unroll
      for (int r = 0; r < 4; ++r) spart[w][m*16 + g*4 + r] = p[m*4 + r];
  }
  __syncthreads();

  if (t < 32) {
    float s = spart[0][t] + spart[1][t] + spart[2][t] + spart[3][t] + bsc[0];
    float mx = s;
    #pragma unroll
    for (int sft = 1; sft < 32; sft <<= 1) mx = fmaxf(mx, __shfl_xor(mx, sft, 64));
    float e = __expf(s - mx);
    float su = e;
    #pragma unroll
    for (int sft = 1; sft < 32; sft <<= 1) su += __shfl_xor(su, sft, 64);
    wexp[t] = e / su;
  }
  __syncthreads();

  #pragma unroll
  for (int pth = 0; pth < 2; ++pth) {
    int d = t + pth*256;
    float s = 0.f;
    #pragma unroll
    for (int k = 0; k < 32; ++k) s += wexp[k] * bf2f(knnb[k*520 + d]);
    attf[(((q>>4)*64 + (d>>3))*16 + (q&15))*8 + (d&7)] = f2bf(s);
  }
}

// ---------------- K3b: out = [q, attended] @ Wc + bc  (256x100, K=1024 MFMA) ----------------
__global__ __launch_bounds__(256) void k3b_cls(const float* __restrict__ Wc,
                                               const unsigned short* __restrict__ qf,
                                               const unsigned short* __restrict__ attf,
                                               const float* __restrict__ bc,
                                               float* __restrict__ out) {
  __shared__ unsigned short wb[128*16*8];   // 32 KB
  int bn = blockIdx.x, t = threadIdx.x;
  int w = t >> 6, l = t & 63, g = l >> 4, c = l & 15;
  #pragma unroll
  for (int i = 0; i < 64; ++i) {
    int d = i*16 + (t>>4); int a = t & 15;
    int col = bn*16 + a;
    float vv = (col < CD) ? Wc[d*CD + col] : 0.f;
    wb[((d>>3)*16 + a)*8 + (d&7)] = f2bf(vv);
  }
  __syncthreads();
  const short8_t* qf8 = (const short8_t*)qf;
  const short8_t* af8 = (const short8_t*)attf;
  const short8_t* wb8 = (const short8_t*)wb;
  f32x4 acc[4];
  #pragma unroll
  for (int m = 0; m < 4; ++m) acc[m] = (f32x4){0.f,0.f,0.f,0.f};
  for (int kt = 0; kt < 32; ++kt) {
    short8_t bfr = wb8[(kt*4 + g)*16 + c];
    const short8_t* asrc = (kt < 16) ? qf8 : af8;
    int kbase = (kt < 16) ? (kt*4 + g) : ((kt-16)*4 + g);
    #pragma unroll
    for (int m = 0; m < 4; ++m) {
      short8_t afr = asrc[((w*4 + m)*64 + kbase)*16 + c];
      acc[m] = mfma_bf16(afr, bfr, acc[m]);
    }
  }
  int col = bn*16 + c;
  if (col < CD) {
    float bias = bc[col];
    #pragma unroll
    for (int m = 0; m < 4; ++m)
      #pragma unroll
      for (int r = 0; r < 4; ++r)
        out[(w*64 + m*16 + g*4 + r)*CD + col] = acc[m][r] + bias;
  }
}

// ---------------- launch ----------------
extern "C" void kernel_launch(void* const* d_in, const int* in_sizes, int n_in,
                              void* d_out, int out_size, void* d_ws, size_t ws_size,
                              hipStream_t stream) {
  const float* qfeat = (const float*)d_in[0];
  const float* keys  = (const float*)d_in[1];
  const float* Wq    = (const float*)d_in[2];
  const float* bq    = (const float*)d_in[3];
  const float* Wm    = (const float*)d_in[4];
  const float* bm    = (const float*)d_in[5];
  const float* Ws    = (const float*)d_in[6];
  const float* bsc   = (const float*)d_in[7];
  const float* Wc    = (const float*)d_in[8];
  const float* bc    = (const float*)d_in[9];
  float* out = (float*)d_out;

  char* ws = (char*)d_ws;
  unsigned short* qf   = (unsigned short*)(ws + 0);          // 262144 B
  float*          qr   = (float*)(ws + 262144);              // 524288 B
  float*          qn   = (float*)(ws + 786432);              // 1024 B
  unsigned short* wmf  = (unsigned short*)(ws + 787456);     // 262144 B
  float*          qq   = (float*)(ws + 1049600);             // 262144 B
  unsigned short* attf = (unsigned short*)(ws + 1311744);    // 262144 B
  int*            fidx = (int*)(ws + 1573888);               // 32768 B
  int*            wtop = (int*)(ws + 1606656);               // 393216 B
  unsigned int*   cand = (unsigned int*)(ws + 1999872);      // 19203072 B

  k0_prep   <<<BQ,       256, 0, stream>>>(qfeat, qr, qf, qn);
  k0b_frag  <<<512,      256, 0, stream>>>(Wm, wmf);
  k_qq      <<<16,       256, 0, stream>>>(Wq, qf, bq, bm, qq);
  k1_sim    <<<NB,       256, 0, stream>>>(keys, qf, cand);
  k2a_reduce<<<BQ*NPART, 256, 0, stream>>>(cand, wtop);
  k2b_rescore<<<BQ,      256, 0, stream>>>(wtop, qr, qn, keys, fidx);
  k3_attn   <<<BQ,       256, 0, stream>>>(keys, qq, wmf, fidx, Ws, bsc, attf);
  k3b_cls   <<<7,        256, 0, stream>>>(Wc, qf, attf, bc, out);
}

// Round 6
// 226.739 us; speedup vs baseline: 1.3003x; 1.3003x over previous
//
#include <hip/hip_runtime.h>
#include <hip/hip_bf16.h>
#include <hip/hip_fp16.h>

// Problem constants
#define BQ    256
#define NKEY  100000
#define DD    512
#define AD    256
#define CD    100
#define KSEL  32
#define KB    64            // keys per K1 block
#define NB    1563          // ceil(NKEY/KB)
#define CPQ   (NB*12)       // cand entries per query = 18756

// k2a/k2b selection params
#define NPART 8             // k2a blocks per query
#define WTOP  12            // per-wave top list emitted by k2a
#define NC2   (NPART*4*WTOP)  // 384 rescore candidates per query
#define TLA   6             // per-lane list depth in k2a

typedef __attribute__((ext_vector_type(8))) short  short8_t;
typedef __attribute__((ext_vector_type(8))) __bf16 bf16x8;
typedef __attribute__((ext_vector_type(4))) float  f32x4;

__device__ __forceinline__ unsigned short f2bf(float x) {
  unsigned int u = __float_as_uint(x);
  return (unsigned short)((u + 0x7FFFu + ((u >> 16) & 1u)) >> 16);  // RTNE
}
__device__ __forceinline__ unsigned short f2bf_n(float x) {
  __bf16 h = (__bf16)x;                 // native cvt, pairs into v_cvt_pk_bf16_f32
  return __builtin_bit_cast(unsigned short, h);
}
__device__ __forceinline__ float bf2f(unsigned short h) {
  return __uint_as_float(((unsigned int)h) << 16);
}
__device__ __forceinline__ f32x4 mfma_bf16(short8_t a, short8_t b, f32x4 c) {
  return __builtin_amdgcn_mfma_f32_16x16x32_bf16(
      __builtin_bit_cast(bf16x8, a), __builtin_bit_cast(bf16x8, b), c, 0, 0, 0);
}
__device__ __forceinline__ float fast_tanh(float x) {
  x = fminf(fmaxf(x, -15.f), 15.f);
  float e = __expf(2.f * x);
  return (e - 1.f) * __builtin_amdgcn_rcpf(e + 1.f);
}
// global -> LDS DMA, 16 bytes per lane; lds dst must be wave-uniform base (+lane*16 by HW)
__device__ __forceinline__ void gload_lds16(const float* g, float* l) {
  __builtin_amdgcn_global_load_lds((const __attribute__((address_space(1))) void*)g,
                                   (__attribute__((address_space(3))) void*)l, 16, 0, 0);
}

template<int T>
__device__ __forceinline__ void topk_insert(float (&v)[T], int (&ix)[T], float val, int idx) {
  if (val <= v[T-1]) return;
  v[T-1] = val; ix[T-1] = idx;
  #pragma unroll
  for (int j = T-1; j > 0; --j) {
    bool sw = v[j] > v[j-1];
    float tv = sw ? v[j] : v[j-1];  float uv = sw ? v[j-1] : v[j];
    int   ti = sw ? ix[j] : ix[j-1]; int  ui = sw ? ix[j-1] : ix[j];
    v[j-1] = tv; v[j] = uv; ix[j-1] = ti; ix[j] = ui;
  }
}

// ---------------- K0: q = relu(query_feat); qn; q -> bf16 fragment layout ----------------
__global__ __launch_bounds__(256) void k0_prep(const float* __restrict__ qfeat,
                                               float* __restrict__ qr,
                                               unsigned short* __restrict__ qf,
                                               float* __restrict__ qn) {
  int b = blockIdx.x, t = threadIdx.x;
  float s = 0.f;
  #pragma unroll
  for (int p = 0; p < 2; ++p) {
    int k = t + p*256;
    float v = qfeat[b*DD + k];
    v = v > 0.f ? v : 0.f;
    qr[b*DD + k] = v;
    qf[(((b>>4)*64 + (k>>3))*16 + (b&15))*8 + (k&7)] = f2bf(v);
    s += v*v;
  }
  __shared__ float red[4];
  #pragma unroll
  for (int st = 1; st < 64; st <<= 1) s += __shfl_xor(s, st, 64);
  if ((t & 63) == 0) red[t>>6] = s;
  __syncthreads();
  if (t == 0) qn[b] = sqrtf(red[0]+red[1]+red[2]+red[3]);
}

// ---------------- K0b: [512,256] fp32 matrix -> bf16 B-fragment layout ----------------
__global__ __launch_bounds__(256) void k0b_frag(const float* __restrict__ W,
                                                unsigned short* __restrict__ wf) {
  int i = blockIdx.x*256 + threadIdx.x;   // i = d*256 + a, 131072 total
  int d = i >> 8, a = i & 255;
  wf[(((a>>4)*64 + (d>>3))*16 + (a&15))*8 + (d&7)] = f2bf(W[i]);
}

// ---------------- K_qq: qq = relu(q) @ Wq + bq + bm  (256x256, K=512 MFMA) ----------------
__global__ __launch_bounds__(256) void k_qq(const float* __restrict__ Wq,
                                            const unsigned short* __restrict__ qf,
                                            const float* __restrict__ bq,
                                            const float* __restrict__ bm,
                                            float* __restrict__ qq) {
  __shared__ unsigned short wb[64*16*8];   // 16 KB
  int bn = blockIdx.x, t = threadIdx.x;
  int w = t >> 6, l = t & 63, g = l >> 4, c = l & 15;
  #pragma unroll
  for (int i = 0; i < 32; ++i) {
    int d = i*16 + (t>>4); int a = t & 15;
    wb[((d>>3)*16 + a)*8 + (d&7)] = f2bf(Wq[d*AD + bn*16 + a]);
  }
  __syncthreads();
  const short8_t* qf8 = (const short8_t*)qf;
  const short8_t* wb8 = (const short8_t*)wb;
  f32x4 acc[4];
  #pragma unroll
  for (int m = 0; m < 4; ++m) acc[m] = (f32x4){0.f,0.f,0.f,0.f};
  for (int kt = 0; kt < 16; ++kt) {
    short8_t bfr = wb8[(kt*4 + g)*16 + c];
    #pragma unroll
    for (int m = 0; m < 4; ++m) {
      short8_t afr = qf8[((w*4 + m)*64 + kt*4 + g)*16 + c];
      acc[m] = mfma_bf16(afr, bfr, acc[m]);
    }
  }
  int col = bn*16 + c;
  float bias = bq[col] + bm[col];
  #pragma unroll
  for (int m = 0; m < 4; ++m)
    #pragma unroll
    for (int r = 0; r < 4; ++r)
      qq[(w*64 + m*16 + g*4 + r)*AD + col] = acc[m][r] + bias;
}

// ---------------- K1: m97-style DMA-staged bf16 GEMM (keys=A via LDS dbuf, queries=B) ----------------
// LDS tile: [64 rows][16 granules of 16B] fp32, granule-swizzled: LDS granule (r, gg)
// holds source granule (gg ^ (r&7)). DMA writes linearly with pre-swizzled SOURCE addr;
// reads apply the same XOR -> bank-balanced ds_read_b128 (rule #21: both-sides-or-neither).
__global__ __launch_bounds__(256) void k1_sim(const float* __restrict__ keys,
                                              const unsigned short* __restrict__ qf,
                                              unsigned int* __restrict__ cand) {
  __shared__ float At[2][64*64];   // 2 x 16 KB
  __shared__ float invkn[64];

  int b = blockIdx.x, t = threadIdx.x;
  int kb0 = b*KB;
  int w = t >> 6, l = t & 63, g = l >> 4, c = l & 15;

  f32x4 acc[4][4];   // [key m-tile][query n-tile]
  #pragma unroll
  for (int m = 0; m < 4; ++m)
    #pragma unroll
    for (int n = 0; n < 4; ++n) acc[m][n] = (f32x4){0.f,0.f,0.f,0.f};
  float ksq = 0.f;   // this wave accumulates norms for rows m==w only

  const short8_t* qf8 = (const short8_t*)qf;

  // staging: 1024 granules (64 rows x 16), 4 DMA per thread, wave-uniform LDS base
  auto stage = [&](int buf, int k0) {
    #pragma unroll
    for (int i = 0; i < 4; ++i) {
      int gidx = i*256 + t;              // granule 0..1023
      int r = gidx >> 4, gg = gidx & 15;
      int row = kb0 + r; row = row < NKEY ? row : NKEY-1;
      const float* src = keys + (size_t)row*DD + k0 + ((gg ^ (r & 7)) << 2);
      float* dst = &At[buf][0] + (i*256 + w*64)*4;   // uniform per wave
      gload_lds16(src, dst);
    }
  };

  stage(0, 0);
  __syncthreads();
  int cur = 0;
  for (int ks8 = 0; ks8 < 8; ++ks8) {
    if (ks8 < 7) stage(cur ^ 1, (ks8 + 1)*64);   // next tile DMA in flight under compute
    int p = c & 7;                                // (m*16+c)&7 == c&7
    #pragma unroll
    for (int kt = 0; kt < 2; ++kt) {
      short8_t bfr[4];
      int chunk = ks8*8 + kt*4 + g;               // 8-dim chunk index
      #pragma unroll
      for (int n = 0; n < 4; ++n) bfr[n] = qf8[((w*4 + n)*64 + chunk)*16 + c];
      int S = kt*8 + g*2;
      int g_lo = S ^ p, g_hi = (S + 1) ^ p;
      #pragma unroll
      for (int m = 0; m < 4; ++m) {
        const float* ab = &At[cur][0] + (m*16 + c)*64;
        float4 lo = *(const float4*)(ab + g_lo*4);
        float4 hi = *(const float4*)(ab + g_hi*4);
        if (m == w) {
          ksq += lo.x*lo.x + lo.y*lo.y + lo.z*lo.z + lo.w*lo.w
               + hi.x*hi.x + hi.y*hi.y + hi.z*hi.z + hi.w*hi.w;
        }
        short8_t af;
        af[0] = (short)f2bf_n(lo.x); af[1] = (short)f2bf_n(lo.y);
        af[2] = (short)f2bf_n(lo.z); af[3] = (short)f2bf_n(lo.w);
        af[4] = (short)f2bf_n(hi.x); af[5] = (short)f2bf_n(hi.y);
        af[6] = (short)f2bf_n(hi.z); af[7] = (short)f2bf_n(hi.w);
        #pragma unroll
        for (int n = 0; n < 4; ++n) acc[m][n] = mfma_bf16(af, bfr[n], acc[m][n]);
      }
    }
    __syncthreads();   // DMA drained + all reads of buf[cur] done
    cur ^= 1;
  }

  // norms: wave w holds rows w*16+c (dims split over g); reduce over g-lanes
  {
    float s = ksq;
    s += __shfl_xor(s, 16, 64);
    s += __shfl_xor(s, 32, 64);
    if (l < 16) invkn[w*16 + l] = s > 0.f ? rsqrtf(s) : 0.f;
  }
  __syncthreads();

  float ikv[16];
  #pragma unroll
  for (int m = 0; m < 4; ++m)
    #pragma unroll
    for (int r = 0; r < 4; ++r) ikv[m*4 + r] = invkn[m*16 + g*4 + r];

  // per-lane branchless top-3 of the lane's 16 keys, per query column
  #pragma unroll
  for (int n = 0; n < 4; ++n) {
    float v1 = -3.0e38f, v2 = -3.0e38f, v3 = -3.0e38f;
    int   i1 = 0, i2 = 0, i3 = 0;
    #pragma unroll
    for (int m = 0; m < 4; ++m)
      #pragma unroll
      for (int r = 0; r < 4; ++r) {
        int lid = m*16 + g*4 + r;
        bool valid = (kb0 + lid) < NKEY;
        float v = valid ? acc[m][n][r] * ikv[m*4 + r] : -3.0e38f;
        bool gt1 = v > v1, gt2 = v > v2, gt3 = v > v3;
        v3 = gt2 ? v2 : (gt3 ? v : v3);  i3 = gt2 ? i2 : (gt3 ? lid : i3);
        v2 = gt1 ? v1 : (gt2 ? v : v2);  i2 = gt1 ? i1 : (gt2 ? lid : i2);
        v1 = gt1 ? v  : v1;              i1 = gt1 ? lid : i1;
      }
    int q = w*64 + n*16 + c;
    unsigned int base = ((unsigned int)q*NB + (unsigned int)b)*12u + (unsigned int)g*3u;
    cand[base + 0] = ((unsigned int)__half_as_ushort(__float2half(v1)) << 16) | (unsigned int)i1;
    cand[base + 1] = ((unsigned int)__half_as_ushort(__float2half(v2)) << 16) | (unsigned int)i2;
    cand[base + 2] = ((unsigned int)__half_as_ushort(__float2half(v3)) << 16) | (unsigned int)i3;
  }
}

// ---------------- K2a: high-occupancy candidate reduce (8 blocks/query, per-wave top-12) ----------------
__global__ __launch_bounds__(256) void k2a_reduce(const unsigned int* __restrict__ cand,
                                                  int* __restrict__ wtop) {
  int bid = blockIdx.x;
  int q = bid >> 3, p = bid & 7;
  int t = threadIdx.x, w = t >> 6, l = t & 63;
  const unsigned int* cq = cand + (size_t)q * CPQ;

  const int PER_PART = (CPQ + NPART - 1) / NPART;   // 2345
  const int PER_WAVE = (PER_PART + 3) / 4;          // 587
  int pbase = p * PER_PART;
  int start = pbase + w * PER_WAVE;
  int end   = pbase + PER_PART;
  if (start + PER_WAVE < end) end = start + PER_WAVE;
  if (end > CPQ) end = CPQ;

  float v[TLA]; int ix[TLA];
  #pragma unroll
  for (int j = 0; j < TLA; ++j) { v[j] = -INFINITY; ix[j] = -1; }
  for (int i = start + l; i < end; i += 64) {
    unsigned int pk = cq[i];
    float val = __half2float(__ushort_as_half((unsigned short)(pk >> 16)));
    int bb = i / 12;                       // compiler magic-mul
    int idx = (bb << 6) | (int)(pk & 63u);
    topk_insert<TLA>(v, ix, val, idx);
  }

  // wave merge: exact wave top-WTOP (heads of sorted per-lane lists)
  int obase = (q * NPART + p) * 4 * WTOP + w * WTOP;
  for (int it = 0; it < WTOP; ++it) {
    float bv = v[0]; int bx = ix[0]; int bl = l;
    #pragma unroll
    for (int sft = 1; sft < 64; sft <<= 1) {
      float ov = __shfl_xor(bv, sft, 64);
      int  oxx = __shfl_xor(bx, sft, 64);
      int  ol  = __shfl_xor(bl, sft, 64);
      bool take = (ov > bv) || (ov == bv && ol < bl);
      if (take) { bv = ov; bx = oxx; bl = ol; }
    }
    if (l == 0) wtop[obase + it] = bx;
    if (l == bl) {
      #pragma unroll
      for (int j = 0; j < TLA-1; ++j) { v[j] = v[j+1]; ix[j] = ix[j+1]; }
      v[TLA-1] = -INFINITY; ix[TLA-1] = -1;
    }
  }
}

// ---------------- K2b: exact fp32 rescore of 384 (pipelined) + final top-32 ----------------
__global__ __launch_bounds__(256) void k2b_rescore(const int* __restrict__ wtop,
                                                   const float* __restrict__ qr,
                                                   const float* __restrict__ qn,
                                                   const float* __restrict__ keys,
                                                   int* __restrict__ fidx) {
  int q = blockIdx.x, t = threadIdx.x, w = t >> 6, l = t & 63;
  __shared__ int   cidL[NC2];
  __shared__ float simx[NC2];
  __shared__ int   sidx[NC2];

  for (int i = t; i < NC2; i += 256) {
    int idx = wtop[q*NC2 + i];
    cidL[i] = (idx < 0 || idx >= NKEY) ? -1 : idx;
  }
  __syncthreads();

  // each lane holds its 8-float slice of the query row
  const float4* q4 = (const float4*)(qr + (size_t)q*DD + l*8);
  float4 qa0 = q4[0], qa1 = q4[1];
  float qnv = qn[q];

  // two-deep pipeline: row loads for candidate i+1 overlap reduce of i
  int idx = cidL[w];
  const float4* kr = (const float4*)(keys + (size_t)(idx < 0 ? 0 : idx)*DD + l*8);
  float4 k0 = kr[0], k1 = kr[1];
  for (int i = 0; i < NC2/4; ++i) {
    int ci = i*4 + w;
    int curidx = idx;
    float4 c0 = k0, c1 = k1;
    if (i + 1 < NC2/4) {
      idx = cidL[(i+1)*4 + w];
      kr = (const float4*)(keys + (size_t)(idx < 0 ? 0 : idx)*DD + l*8);
      k0 = kr[0]; k1 = kr[1];
    }
    float dot = qa0.x*c0.x + qa0.y*c0.y + qa0.z*c0.z + qa0.w*c0.w
              + qa1.x*c1.x + qa1.y*c1.y + qa1.z*c1.z + qa1.w*c1.w;
    float ks  = c0.x*c0.x + c0.y*c0.y + c0.z*c0.z + c0.w*c0.w
              + c1.x*c1.x + c1.y*c1.y + c1.z*c1.z + c1.w*c1.w;
    #pragma unroll
    for (int sft = 1; sft < 64; sft <<= 1) {
      dot += __shfl_xor(dot, sft, 64);
      ks  += __shfl_xor(ks,  sft, 64);
    }
    if (l == 0) {
      float den = fmaxf(qnv * sqrtf(ks), 1e-8f);
      simx[ci] = (curidx < 0) ? -1e30f : dot/den;
      sidx[ci] = (curidx < 0) ? 0 : curidx;
    }
  }
  __syncthreads();

  // wave 0: exact top-32 of 384, tie-break value desc then index asc (lax.top_k)
  if (w == 0) {
    float a[6]; int id[6];
    #pragma unroll
    for (int j = 0; j < 6; ++j) { a[j] = simx[j*64 + l]; id[j] = sidx[j*64 + l]; }
    for (int it = 0; it < KSEL; ++it) {
      float bv = a[0]; int bx = id[0]; int bslot = 0;
      #pragma unroll
      for (int j = 1; j < 6; ++j) {
        bool take = (a[j] > bv) || (a[j] == bv && id[j] < bx);
        bv = take ? a[j] : bv; bx = take ? id[j] : bx; bslot = take ? j : bslot;
      }
      int bl = l;
      #pragma unroll
      for (int sft = 1; sft < 64; sft <<= 1) {
        float ov = __shfl_xor(bv, sft, 64);
        int  oxx = __shfl_xor(bx, sft, 64);
        int  ol  = __shfl_xor(bl, sft, 64);
        bool take = (ov > bv) || (ov == bv && oxx < bx);
        if (take) { bv = ov; bx = oxx; bl = ol; }
      }
      if (l == 0) fidx[q*KSEL + it] = bx;
      if (l == bl) {
        #pragma unroll
        for (int j = 0; j < 6; ++j) if (j == bslot) a[j] = -INFINITY;
      }
    }
  }
}

// ---------------- K3a: gather knn, MFMA knn@Wm, tanh/score/softmax, attended -> attf ----------------
__global__ __launch_bounds__(256) void k3_attn(const float* __restrict__ keys,
                                               const float* __restrict__ qq,
                                               const unsigned short* __restrict__ wmf,
                                               const int* __restrict__ fidx,
                                               const float* __restrict__ Ws,
                                               const float* __restrict__ bsc,
                                               unsigned short* __restrict__ attf) {
  int q = blockIdx.x, t = threadIdx.x, w = t >> 6, l = t & 63, g = l >> 4, c = l & 15;
  __shared__ float qqb[256];
  __shared__ float wsl[256];
  __shared__ unsigned short knnb[32*520];
  __shared__ float spart[4][32];
  __shared__ float wexp[32];
  __shared__ int fl[32];

  if (t < 32) fl[t] = fidx[q*KSEL + t];
  qqb[t] = qq[q*AD + t];
  wsl[t] = Ws[t];
  __syncthreads();

  // vectorized gather: 2 rows per pass, 128 lanes x float4 per row
  #pragma unroll 4
  for (int rr = 0; rr < 32; rr += 2) {
    int r = rr + (t >> 7);
    int row = fl[r];
    int d4 = t & 127;
    float4 v = *(const float4*)(keys + (size_t)row*DD + d4*4);
    ushort4 h; h.x = f2bf_n(v.x); h.y = f2bf_n(v.y); h.z = f2bf_n(v.z); h.w = f2bf_n(v.w);
    *(ushort4*)&knnb[r*520 + d4*4] = h;
  }
  __syncthreads();

  f32x4 acc[2][4];
  #pragma unroll
  for (int m = 0; m < 2; ++m)
    #pragma unroll
    for (int n = 0; n < 4; ++n) acc[m][n] = (f32x4){0.f,0.f,0.f,0.f};
  const short8_t* wmf8 = (const short8_t*)wmf;
  for (int ks = 0; ks < 16; ++ks) {
    short8_t af[2], bf[4];
    #pragma unroll
    for (int m = 0; m < 2; ++m) af[m] = *(const short8_t*)&knnb[(m*16 + c)*520 + ks*32 + g*8];
    #pragma unroll
    for (int n = 0; n < 4; ++n) bf[n] = wmf8[((w*4 + n)*64 + ks*4 + g)*16 + c];
    #pragma unroll
    for (int m = 0; m < 2; ++m)
      #pragma unroll
      for (int n = 0; n < 4; ++n) acc[m][n] = mfma_bf16(af[m], bf[n], acc[m][n]);
  }

  float p[8] = {0.f,0.f,0.f,0.f,0.f,0.f,0.f,0.f};
  #pragma unroll
  for (int n = 0; n < 4; ++n) {
    int a = w*64 + n*16 + c;
    float qv = qqb[a], wv = wsl[a];
    #pragma unroll
    for (int m = 0; m < 2; ++m)
      #pragma unroll
      for (int r = 0; r < 4; ++r)
        p[m*4 + r] += fast_tanh(acc[m][n][r] + qv) * wv;
  }
  #pragma unroll
  for (int sft = 1; sft < 16; sft <<= 1)
    #pragma unroll
    for (int i = 0; i < 8; ++i) p[i] += __shfl_xor(p[i], sft, 64);
  if (c == 0) {
    #pragma unroll
    for (int m = 0; m < 2; ++m)
      #pragma unroll
      for (int r = 0; r < 4; ++r) spart[w][m*16 + g*4 + r] = p[m*4 + r];
  }
  __syncthreads();

  if (t < 32) {
    float s = spart[0][t] + spart[1][t] + spart[2][t] + spart[3][t] + bsc[0];
    float mx = s;
    #pragma unroll
    for (int sft = 1; sft < 32; sft <<= 1) mx = fmaxf(mx, __shfl_xor(mx, sft, 64));
    float e = __expf(s - mx);
    float su = e;
    #pragma unroll
    for (int sft = 1; sft < 32; sft <<= 1) su += __shfl_xor(su, sft, 64);
    wexp[t] = e / su;
  }
  __syncthreads();

  #pragma unroll
  for (int pth = 0; pth < 2; ++pth) {
    int d = t + pth*256;
    float s = 0.f;
    #pragma unroll
    for (int k = 0; k < 32; ++k) s += wexp[k] * bf2f(knnb[k*520 + d]);
    attf[(((q>>4)*64 + (d>>3))*16 + (q&15))*8 + (d&7)] = f2bf(s);
  }
}

// ---------------- K3b: out = [q, attended] @ Wc + bc  (256x100, K=1024 MFMA) ----------------
__global__ __launch_bounds__(256) void k3b_cls(const float* __restrict__ Wc,
                                               const unsigned short* __restrict__ qf,
                                               const unsigned short* __restrict__ attf,
                                               const float* __restrict__ bc,
                                               float* __restrict__ out) {
  __shared__ unsigned short wb[128*16*8];   // 32 KB
  int bn = blockIdx.x, t = threadIdx.x;
  int w = t >> 6, l = t & 63, g = l >> 4, c = l & 15;
  #pragma unroll
  for (int i = 0; i < 64; ++i) {
    int d = i*16 + (t>>4); int a = t & 15;
    int col = bn*16 + a;
    float vv = (col < CD) ? Wc[d*CD + col] : 0.f;
    wb[((d>>3)*16 + a)*8 + (d&7)] = f2bf(vv);
  }
  __syncthreads();
  const short8_t* qf8 = (const short8_t*)qf;
  const short8_t* af8 = (const short8_t*)attf;
  const short8_t* wb8 = (const short8_t*)wb;
  f32x4 acc[4];
  #pragma unroll
  for (int m = 0; m < 4; ++m) acc[m] = (f32x4){0.f,0.f,0.f,0.f};
  for (int kt = 0; kt < 32; ++kt) {
    short8_t bfr = wb8[(kt*4 + g)*16 + c];
    const short8_t* asrc = (kt < 16) ? qf8 : af8;
    int kbase = (kt < 16) ? (kt*4 + g) : ((kt-16)*4 + g);
    #pragma unroll
    for (int m = 0; m < 4; ++m) {
      short8_t afr = asrc[((w*4 + m)*64 + kbase)*16 + c];
      acc[m] = mfma_bf16(afr, bfr, acc[m]);
    }
  }
  int col = bn*16 + c;
  if (col < CD) {
    float bias = bc[col];
    #pragma unroll
    for (int m = 0; m < 4; ++m)
      #pragma unroll
      for (int r = 0; r < 4; ++r)
        out[(w*64 + m*16 + g*4 + r)*CD + col] = acc[m][r] + bias;
  }
}

// ---------------- launch ----------------
extern "C" void kernel_launch(void* const* d_in, const int* in_sizes, int n_in,
                              void* d_out, int out_size, void* d_ws, size_t ws_size,
                              hipStream_t stream) {
  const float* qfeat = (const float*)d_in[0];
  const float* keys  = (const float*)d_in[1];
  const float* Wq    = (const float*)d_in[2];
  const float* bq    = (const float*)d_in[3];
  const float* Wm    = (const float*)d_in[4];
  const float* bm    = (const float*)d_in[5];
  const float* Ws    = (const float*)d_in[6];
  const float* bsc   = (const float*)d_in[7];
  const float* Wc    = (const float*)d_in[8];
  const float* bc    = (const float*)d_in[9];
  float* out = (float*)d_out;

  char* ws = (char*)d_ws;
  unsigned short* qf   = (unsigned short*)(ws + 0);          // 262144 B
  float*          qr   = (float*)(ws + 262144);              // 524288 B
  float*          qn   = (float*)(ws + 786432);              // 1024 B
  unsigned short* wmf  = (unsigned short*)(ws + 787456);     // 262144 B
  float*          qq   = (float*)(ws + 1049600);             // 262144 B
  unsigned short* attf = (unsigned short*)(ws + 1311744);    // 262144 B
  int*            fidx = (int*)(ws + 1573888);               // 32768 B
  int*            wtop = (int*)(ws + 1606656);               // 393216 B
  unsigned int*   cand = (unsigned int*)(ws + 1999872);      // 19203072 B

  k0_prep   <<<BQ,       256, 0, stream>>>(qfeat, qr, qf, qn);
  k0b_frag  <<<512,      256, 0, stream>>>(Wm, wmf);
  k_qq      <<<16,       256, 0, stream>>>(Wq, qf, bq, bm, qq);
  k1_sim    <<<NB,       256, 0, stream>>>(keys, qf, cand);
  k2a_reduce<<<BQ*NPART, 256, 0, stream>>>(cand, wtop);
  k2b_rescore<<<BQ,      256, 0, stream>>>(wtop, qr, qn, keys, fidx);
  k3_attn   <<<BQ,       256, 0, stream>>>(keys, qq, wmf, fidx, Ws, bsc, attf);
  k3b_cls   <<<7,        256, 0, stream>>>(Wc, qf, attf, bc, out);
}